// Round 1
// baseline (253.282 us; speedup 1.0000x reference)
//
#include <hip/hip_runtime.h>

typedef short v8s __attribute__((ext_vector_type(8)));
typedef float v4f __attribute__((ext_vector_type(4)));
typedef unsigned short u16;
typedef unsigned int u32;
typedef u16 v4u __attribute__((ext_vector_type(4)));

#define SS 4096
#define DD 256
#define QB 64
#define KVB 64
#define NKV 64

__device__ __forceinline__ u16 f2bf(float f) {
  u32 u = __builtin_bit_cast(u32, f);
  return (u16)((u + 0x7FFFu + ((u >> 16) & 1u)) >> 16);
}

__device__ __forceinline__ void gload16(const u16* g, u16* l) {
  __builtin_amdgcn_global_load_lds((const __attribute__((address_space(1))) u32*)g,
                                   (__attribute__((address_space(3))) u32*)l, 16, 0, 0);
}

// ---- transpose + cast weights: wt[p][n][k] = W_p[k][n] in bf16 ----
__global__ void wcast_kernel(const float* __restrict__ Wq, const float* __restrict__ Wk,
                             const float* __restrict__ Wv, u16* __restrict__ wt) {
  int f = blockIdx.x * 256 + threadIdx.x;   // 3*65536 total
  int p = f >> 16, rem = f & 65535, n = rem >> 8, k = rem & 255;
  const float* W = (p == 0) ? Wq : ((p == 1) ? Wk : Wv);
  wt[f] = f2bf(W[k * 256 + n]);
}

// ---- QKV projection: q,k row-major bf16 (scale folded into q); v transposed ----
__global__ __launch_bounds__(256) void proj_kernel(
    const float* __restrict__ x, const u16* __restrict__ wt,
    const float* __restrict__ bq, const float* __restrict__ bk, const float* __restrict__ bv,
    u16* __restrict__ qg, u16* __restrict__ kg, u16* __restrict__ vtg) {
  __shared__ u16 xs[64 * 256];
  const int tid = threadIdx.x;
  const int lane = tid & 63, w = tid >> 6, g = lane >> 4, l15 = lane & 15;
  const int tok0 = blockIdx.x * 64;

#pragma unroll
  for (int it = 0; it < 8; ++it) {
    int idx = it * 256 + tid;           // 0..2047 chunks of 8 elems
    int r = idx >> 5, d0 = (idx & 31) << 3;
    const float* src = x + (size_t)(tok0 + r) * DD + d0;
    float4 a = *(const float4*)src;
    float4 b = *(const float4*)(src + 4);
    v8s pk;
    pk[0] = (short)f2bf(a.x); pk[1] = (short)f2bf(a.y);
    pk[2] = (short)f2bf(a.z); pk[3] = (short)f2bf(a.w);
    pk[4] = (short)f2bf(b.x); pk[5] = (short)f2bf(b.y);
    pk[6] = (short)f2bf(b.z); pk[7] = (short)f2bf(b.w);
    *(v8s*)(xs + r * DD + (((d0 >> 3) ^ (r & 7)) << 3)) = pk;
  }
  __syncthreads();

  v8s af[8];
  const int arow = 16 * w + l15;
#pragma unroll
  for (int c = 0; c < 8; ++c)
    af[c] = *(const v8s*)(xs + arow * DD + ((((g + 4 * c) ^ (arow & 7))) << 3));

  for (int p = 0; p < 3; ++p) {
    const u16* wbase = wt + p * 65536;
    const float* bias = (p == 0) ? bq : ((p == 1) ? bk : bv);
    v4f acc[16];
    const v4f vzero = {0.f, 0.f, 0.f, 0.f};
#pragma unroll
    for (int t = 0; t < 16; ++t) acc[t] = vzero;
#pragma unroll
    for (int t = 0; t < 16; ++t) {
      const u16* wrow = wbase + (l15 + 16 * t) * 256;
#pragma unroll
      for (int c = 0; c < 8; ++c) {
        v8s bf = *(const v8s*)(wrow + 8 * g + 32 * c);
        acc[t] = __builtin_amdgcn_mfma_f32_16x16x32_bf16(af[c], bf, acc[t], 0, 0, 0);
      }
    }
    if (p == 0) {
#pragma unroll
      for (int t = 0; t < 16; ++t) {
        int n = l15 + 16 * t;
        float bb = bias[n];
#pragma unroll
        for (int r = 0; r < 4; ++r)
          qg[(size_t)(tok0 + 16 * w + 4 * g + r) * DD + n] = f2bf((acc[t][r] + bb) * 0.0625f);
      }
    } else if (p == 1) {
#pragma unroll
      for (int t = 0; t < 16; ++t) {
        int n = l15 + 16 * t;
        float bb = bias[n];
#pragma unroll
        for (int r = 0; r < 4; ++r)
          kg[(size_t)(tok0 + 16 * w + 4 * g + r) * DD + n] = f2bf(acc[t][r] + bb);
      }
    } else {
      const int b = tok0 >> 12;
      const int s0 = (tok0 & 4095) + 16 * w + 4 * g;
#pragma unroll
      for (int t = 0; t < 16; ++t) {
        int n = l15 + 16 * t;
        float bb = bias[n];
        v4u pk;
#pragma unroll
        for (int r = 0; r < 4; ++r) pk[r] = f2bf(acc[t][r] + bb);
        *(v4u*)(vtg + (size_t)(b * DD + n) * SS + s0) = pk;
      }
    }
  }
}

// ---- flash attention: 4 waves x 16 q-rows, KV double-buffered, swizzled LDS ----
__global__ __launch_bounds__(256) void attn_kernel(
    const u16* __restrict__ qg, const u16* __restrict__ kg,
    const u16* __restrict__ vtg, float* __restrict__ out) {
  extern __shared__ u16 sm[];
  u16* kb = sm;              // [2][64*256] swizzled K tiles
  u16* vt = sm + 32768;      // [2][256*64] swizzled V^T tiles
  u16* pb = sm + 65536;      // [4][16*64]  per-wave P tiles

  const int jj = blockIdx.x;
  const int logical = (jj & 7) * 32 + (jj >> 3);   // XCD x -> batch x/2, L2-resident K/V
  const int b = logical >> 6;
  const int qt = logical & 63;
  const int tid = threadIdx.x;
  const int lane = tid & 63, w = tid >> 6, g = lane >> 4, l15 = lane & 15;

  const u16* qbase = qg + (size_t)(b * SS + qt * QB) * DD;
  const u16* kbase = kg + (size_t)b * SS * DD;
  const u16* vbase = vtg + (size_t)b * DD * SS;

  // stage Q tile (borrow kb buf0), hoist Q fragments to registers
#pragma unroll
  for (int it = 0; it < 8; ++it) {
    int idx = it * 256 + tid;
    int r = idx >> 5, db = idx & 31;
    gload16(qbase + r * DD + ((db ^ (r & 7)) << 3), kb + idx * 8);
  }
  __syncthreads();
  v8s qf[8];
  {
    const int r = 16 * w + l15;
#pragma unroll
    for (int c = 0; c < 8; ++c)
      qf[c] = *(const v8s*)(kb + r * DD + ((((g + 4 * c) ^ (r & 7))) << 3));
  }
  __syncthreads();

  float mrow[4], lrow[4];
  v4f oacc[16];
  const v4f vzero = {0.f, 0.f, 0.f, 0.f};
#pragma unroll
  for (int r = 0; r < 4; ++r) { mrow[r] = -1e30f; lrow[r] = 0.f; }
#pragma unroll
  for (int t = 0; t < 16; ++t) oacc[t] = vzero;

  // prologue: stage kv-tile 0 into buffer 0
#pragma unroll
  for (int it = 0; it < 8; ++it) {
    int idx = it * 256 + tid;
    int r = idx >> 5, db = idx & 31;
    gload16(kbase + r * DD + ((db ^ (r & 7)) << 3), kb + idx * 8);
  }
#pragma unroll
  for (int it = 0; it < 8; ++it) {
    int idx = it * 256 + tid;
    int d = idx >> 3, jb2 = idx & 7;
    gload16(vbase + (size_t)d * SS + ((jb2 ^ (d & 7)) << 3), vt + idx * 8);
  }

  for (int kt = 0; kt < NKV; ++kt) {
    const int cur = kt & 1;
    __syncthreads();                       // drains stage(kt); buf `cur` ready
    if (kt + 1 < NKV) {                    // prefetch next tile, flies under compute
      const u16* ks = kbase + (size_t)(kt + 1) * KVB * DD;
      u16* kd = kb + (cur ^ 1) * 16384;
      const u16* vs = vbase + (kt + 1) * KVB;
      u16* vd = vt + (cur ^ 1) * 16384;
#pragma unroll
      for (int it = 0; it < 8; ++it) {
        int idx = it * 256 + tid;
        int r = idx >> 5, db = idx & 31;
        gload16(ks + r * DD + ((db ^ (r & 7)) << 3), kd + idx * 8);
      }
#pragma unroll
      for (int it = 0; it < 8; ++it) {
        int idx = it * 256 + tid;
        int d = idx >> 3, jb2 = idx & 7;
        gload16(vs + (size_t)d * SS + ((jb2 ^ (d & 7)) << 3), vd + idx * 8);
      }
    }
    const u16* kc = kb + cur * 16384;
    const u16* vc = vt + cur * 16384;

    // S = Q K^T (scale pre-folded into q)
    v4f sacc[4];
#pragma unroll
    for (int t = 0; t < 4; ++t) sacc[t] = vzero;
#pragma unroll
    for (int c = 0; c < 8; ++c) {
#pragma unroll
      for (int t = 0; t < 4; ++t) {
        const int krow = l15 + 16 * t;
        v8s bf = *(const v8s*)(kc + krow * DD + ((((g + 4 * c) ^ (krow & 7))) << 3));
        sacc[t] = __builtin_amdgcn_mfma_f32_16x16x32_bf16(qf[c], bf, sacc[t], 0, 0, 0);
      }
    }

    // online softmax (rows live in 16-lane groups)
    float mx[4];
#pragma unroll
    for (int r = 0; r < 4; ++r)
      mx[r] = fmaxf(fmaxf(sacc[0][r], sacc[1][r]), fmaxf(sacc[2][r], sacc[3][r]));
#pragma unroll
    for (int msk = 1; msk <= 8; msk <<= 1) {
#pragma unroll
      for (int r = 0; r < 4; ++r) mx[r] = fmaxf(mx[r], __shfl_xor(mx[r], msk));
    }
    float sc[4];
#pragma unroll
    for (int r = 0; r < 4; ++r) {
      float mn = fmaxf(mrow[r], mx[r]);
      sc[r] = __expf(mrow[r] - mn);
      mrow[r] = mn;
    }
    float ps[4][4];
#pragma unroll
    for (int t = 0; t < 4; ++t)
#pragma unroll
      for (int r = 0; r < 4; ++r) ps[t][r] = __expf(sacc[t][r] - mrow[r]);
    float rs[4];
#pragma unroll
    for (int r = 0; r < 4; ++r) rs[r] = (ps[0][r] + ps[1][r]) + (ps[2][r] + ps[3][r]);
#pragma unroll
    for (int msk = 1; msk <= 8; msk <<= 1) {
#pragma unroll
      for (int r = 0; r < 4; ++r) rs[r] += __shfl_xor(rs[r], msk);
    }
#pragma unroll
    for (int r = 0; r < 4; ++r) lrow[r] = lrow[r] * sc[r] + rs[r];
#pragma unroll
    for (int t = 0; t < 16; ++t) {
#pragma unroll
      for (int r = 0; r < 4; ++r) oacc[t][r] *= sc[r];
    }

    // P -> per-wave LDS (swizzled), re-read as MFMA A-fragments (no barrier: same wave)
    u16* pw = pb + w * 1024;
#pragma unroll
    for (int t = 0; t < 4; ++t) {
      const int cc = l15 + 16 * t;
#pragma unroll
      for (int r = 0; r < 4; ++r) {
        const int row = 4 * g + r;
        pw[row * 64 + ((((cc >> 3) ^ (row & 7)) << 3) | (cc & 7))] = f2bf(ps[t][r]);
      }
    }
#pragma unroll
    for (int c2 = 0; c2 < 2; ++c2) {
      v8s pa = *(const v8s*)(pw + l15 * 64 + ((((g + 4 * c2) ^ (l15 & 7))) << 3));
#pragma unroll
      for (int t = 0; t < 16; ++t) {
        const int d = l15 + 16 * t;
        v8s bv = *(const v8s*)(vc + d * 64 + ((((g + 4 * c2) ^ (d & 7))) << 3));
        oacc[t] = __builtin_amdgcn_mfma_f32_16x16x32_bf16(pa, bv, oacc[t], 0, 0, 0);
      }
    }
  }

  float inv[4];
#pragma unroll
  for (int r = 0; r < 4; ++r) inv[r] = 1.0f / lrow[r];
  float* ob = out + (size_t)(b * SS + qt * QB + 16 * w) * DD;
#pragma unroll
  for (int t = 0; t < 16; ++t)
#pragma unroll
    for (int r = 0; r < 4; ++r)
      ob[(4 * g + r) * DD + l15 + 16 * t] = oacc[t][r] * inv[r];
}

extern "C" void kernel_launch(void* const* d_in, const int* in_sizes, int n_in,
                              void* d_out, int out_size, void* d_ws, size_t ws_size,
                              hipStream_t stream) {
  const float* x  = (const float*)d_in[0];
  const float* Wq = (const float*)d_in[1];
  const float* bq = (const float*)d_in[2];
  const float* Wk = (const float*)d_in[3];
  const float* bk = (const float*)d_in[4];
  const float* Wv = (const float*)d_in[5];
  const float* bv = (const float*)d_in[6];
  float* out = (float*)d_out;
  char* ws = (char*)d_ws;

  u16* wt  = (u16*)ws;                               // 393,216 B
  u16* qg  = (u16*)(ws + 393216);                    // 8,388,608 B
  u16* kg  = (u16*)(ws + 393216 + 8388608);          // 8,388,608 B
  u16* vtg = (u16*)(ws + 393216 + 2 * 8388608);      // 8,388,608 B  (total ~25.6 MB)

  (void)hipFuncSetAttribute((const void*)attn_kernel,
                            hipFuncAttributeMaxDynamicSharedMemorySize, 139264);

  wcast_kernel<<<dim3(768), dim3(256), 0, stream>>>(Wq, Wk, Wv, wt);
  proj_kernel<<<dim3(256), dim3(256), 0, stream>>>(x, wt, bq, bk, bv, qg, kg, vtg);
  attn_kernel<<<dim3(256), dim3(256), 139264, stream>>>(qg, kg, vtg, out);
}

// Round 2
// 176.646 us; speedup vs baseline: 1.4338x; 1.4338x over previous
//
#include <hip/hip_runtime.h>

typedef short v8s __attribute__((ext_vector_type(8)));
typedef float v4f __attribute__((ext_vector_type(4)));
typedef unsigned short u16;
typedef unsigned int u32;
typedef u16 v4u __attribute__((ext_vector_type(4)));

#define SS 4096
#define DD 256
#define QB 128
#define KVB 64

__device__ __forceinline__ u16 f2bf(float f) {
  u32 u = __builtin_bit_cast(u32, f);
  return (u16)((u + 0x7FFFu + ((u >> 16) & 1u)) >> 16);
}

__device__ __forceinline__ void gload16(const u16* g, u16* l) {
  __builtin_amdgcn_global_load_lds((const __attribute__((address_space(1))) u32*)g,
                                   (__attribute__((address_space(3))) u32*)l, 16, 0, 0);
}

// ---- transpose + cast weights: wt[p][n][k] = W_p[k][n] in bf16 ----
__global__ void wcast_kernel(const float* __restrict__ Wq, const float* __restrict__ Wk,
                             const float* __restrict__ Wv, u16* __restrict__ wt) {
  int f = blockIdx.x * 256 + threadIdx.x;   // 3*65536 total
  int p = f >> 16, rem = f & 65535, n = rem >> 8, k = rem & 255;
  const float* W = (p == 0) ? Wq : ((p == 1) ? Wk : Wv);
  wt[f] = f2bf(W[k * 256 + n]);
}

// ---- QKV projection: waves split N (W-frag reads not wave-redundant) ----
// q gets scale*log2e folded in; v written transposed vT[b][D][S].
__global__ __launch_bounds__(256) void proj_kernel(
    const float* __restrict__ x, const u16* __restrict__ wt,
    const float* __restrict__ bq, const float* __restrict__ bk, const float* __restrict__ bv,
    u16* __restrict__ qg, u16* __restrict__ kg, u16* __restrict__ vtg) {
  __shared__ u16 xs[64 * 256];
  const int tid = threadIdx.x;
  const int lane = tid & 63, w = tid >> 6, g = lane >> 4, l15 = lane & 15;
  const int tok0 = blockIdx.x * 64;

#pragma unroll
  for (int it = 0; it < 8; ++it) {
    int idx = it * 256 + tid;
    int r = idx >> 5, d0 = (idx & 31) << 3;
    const float* src = x + (size_t)(tok0 + r) * DD + d0;
    float4 a = *(const float4*)src;
    float4 bb = *(const float4*)(src + 4);
    v8s pk;
    pk[0] = (short)f2bf(a.x);  pk[1] = (short)f2bf(a.y);
    pk[2] = (short)f2bf(a.z);  pk[3] = (short)f2bf(a.w);
    pk[4] = (short)f2bf(bb.x); pk[5] = (short)f2bf(bb.y);
    pk[6] = (short)f2bf(bb.z); pk[7] = (short)f2bf(bb.w);
    *(v8s*)(xs + r * DD + (((d0 >> 3) ^ (r & 7)) << 3)) = pk;
  }
  __syncthreads();

  // A-frags: all 64 tokens (4 M-frags) x 8 k-chunks, kept in regs across p
  v8s af[4][8];
#pragma unroll
  for (int m = 0; m < 4; ++m) {
    const int row = 16 * m + l15;
#pragma unroll
    for (int c = 0; c < 8; ++c)
      af[m][c] = *(const v8s*)(xs + row * DD + ((((4 * c + g) ^ (row & 7))) << 3));
  }

  const float SCL = 0.0625f * 1.44269504088896f;  // 1/sqrt(D) * log2(e)
  for (int p = 0; p < 3; ++p) {
    const u16* wbase = wt + p * 65536;
    const float* bias = (p == 0) ? bq : ((p == 1) ? bk : bv);
    v4f acc[4][4];
    const v4f vzero = {0.f, 0.f, 0.f, 0.f};
#pragma unroll
    for (int m = 0; m < 4; ++m)
#pragma unroll
      for (int t = 0; t < 4; ++t) acc[m][t] = vzero;
#pragma unroll
    for (int t = 0; t < 4; ++t) {
      const int n = 64 * w + 16 * t + l15;
      const u16* wrow = wbase + n * 256;
#pragma unroll
      for (int c = 0; c < 8; ++c) {
        v8s bf = *(const v8s*)(wrow + 8 * g + 32 * c);
#pragma unroll
        for (int m = 0; m < 4; ++m)
          acc[m][t] = __builtin_amdgcn_mfma_f32_16x16x32_bf16(af[m][c], bf, acc[m][t], 0, 0, 0);
      }
    }
    if (p == 0) {
#pragma unroll
      for (int t = 0; t < 4; ++t) {
        int n = 64 * w + 16 * t + l15;
        float bb = bias[n];
#pragma unroll
        for (int m = 0; m < 4; ++m)
#pragma unroll
          for (int r = 0; r < 4; ++r)
            qg[(size_t)(tok0 + 16 * m + 4 * g + r) * DD + n] = f2bf((acc[m][t][r] + bb) * SCL);
      }
    } else if (p == 1) {
#pragma unroll
      for (int t = 0; t < 4; ++t) {
        int n = 64 * w + 16 * t + l15;
        float bb = bias[n];
#pragma unroll
        for (int m = 0; m < 4; ++m)
#pragma unroll
          for (int r = 0; r < 4; ++r)
            kg[(size_t)(tok0 + 16 * m + 4 * g + r) * DD + n] = f2bf(acc[m][t][r] + bb);
      }
    } else {
      const int b = tok0 >> 12;
      const int s0 = tok0 & 4095;
#pragma unroll
      for (int t = 0; t < 4; ++t) {
        int n = 64 * w + 16 * t + l15;
        float bb = bias[n];
#pragma unroll
        for (int m = 0; m < 4; ++m) {
          v4u pk;
#pragma unroll
          for (int r = 0; r < 4; ++r) pk[r] = f2bf(acc[m][t][r] + bb);
          *(v4u*)(vtg + (size_t)(b * DD + n) * SS + s0 + 16 * m + 4 * g) = pk;
        }
      }
    }
  }
}

// ---- flash attention, swapped-QK^T, 4 waves x 32 q-rows, kv-split partials ----
#define STAGE(kt_, buf_)                                                         \
  {                                                                              \
    const int kt__ = (kt_); const int buf__ = (buf_);                            \
    _Pragma("unroll")                                                            \
    for (int it = 0; it < 8; ++it) {                                             \
      int idx = it * 256 + tid;                                                  \
      int r = idx >> 5, db = idx & 31;                                           \
      gload16(kbase + (size_t)(kt__ * 64 + r) * DD + ((db ^ (r & 7)) << 3),      \
              kb + buf__ * 16384 + idx * 8);                                     \
    }                                                                            \
    _Pragma("unroll")                                                            \
    for (int it = 0; it < 8; ++it) {                                             \
      int idx = it * 256 + tid;                                                  \
      int d = idx >> 3, jb = idx & 7;                                            \
      gload16(vbase + (size_t)d * SS + kt__ * 64 + ((jb ^ (d & 7)) << 3),        \
              vt + buf__ * 16384 + idx * 8);                                     \
    }                                                                            \
  }

__global__ __launch_bounds__(256) void attn_kernel(
    const u16* __restrict__ qg, const u16* __restrict__ kg, const u16* __restrict__ vtg,
    float* __restrict__ o0, float* __restrict__ o1, float* __restrict__ ml, int nsplit) {
  extern __shared__ u16 sm[];
  u16* kb = sm;                 // [2][64*256]   swizzled K tiles (also Q staging)
  u16* vt = sm + 32768;         // [2][256*64]   swizzled V^T tiles
  u16* pb = sm + 65536;         // [4][32*64]    per-wave P tiles

  const int bid = blockIdx.x;
  int b, slice, qt;
  if (nsplit == 2) { b = (bid >> 1) & 3; slice = bid & 1; qt = bid >> 3; }
  else             { b = (bid >> 1) & 3; slice = 0;       qt = ((bid >> 3) << 1) | (bid & 1); }
  const int NT = 64 / nsplit;
  const int koff = slice * (SS / nsplit);

  const int tid = threadIdx.x;
  const int lane = tid & 63, w = tid >> 6, g = lane >> 4, l15 = lane & 15;

  const u16* qbase = qg + (size_t)(b * SS + qt * QB) * DD;
  const u16* kbase = kg + (size_t)(b * SS + koff) * DD;
  const u16* vbase = vtg + (size_t)b * DD * SS + koff;

  // stage Q tile (128x256) into kb[0..1], hoist Q B-fragments to registers
#pragma unroll
  for (int it = 0; it < 16; ++it) {
    int idx = it * 256 + tid;
    int r = idx >> 5, db = idx & 31;
    gload16(qbase + (size_t)r * DD + ((db ^ (r & 7)) << 3), kb + idx * 8);
  }
  __syncthreads();
  v8s qf[2][8];
#pragma unroll
  for (int j = 0; j < 2; ++j) {
    const int row = 32 * w + 16 * j + l15;
#pragma unroll
    for (int c = 0; c < 8; ++c)
      qf[j][c] = *(const v8s*)(kb + row * DD + ((((4 * c + g) ^ (row & 7))) << 3));
  }
  __syncthreads();

  float mrow[2], lrow[2];
  v4f oacc[2][16];
  const v4f vzero = {0.f, 0.f, 0.f, 0.f};
#pragma unroll
  for (int j = 0; j < 2; ++j) { mrow[j] = -1e30f; lrow[j] = 0.f; }
#pragma unroll
  for (int m = 0; m < 2; ++m)
#pragma unroll
    for (int t = 0; t < 16; ++t) oacc[m][t] = vzero;

  STAGE(0, 0);

  for (int kt = 0; kt < NT; ++kt) {
    const int cur = kt & 1;
    __syncthreads();                       // drains stage(kt); buf `cur` ready
    if (kt + 1 < NT) STAGE(kt + 1, cur ^ 1);
    const u16* kc = kb + cur * 16384;
    const u16* vc = vt + cur * 16384;

    // S^T = K @ Q^T : lane holds S[key=16t+4g+r][qrow=32w+16j+l15]
    v4f sacc[4][2];
#pragma unroll
    for (int t = 0; t < 4; ++t)
#pragma unroll
      for (int j = 0; j < 2; ++j) sacc[t][j] = vzero;
#pragma unroll
    for (int c = 0; c < 8; ++c) {
#pragma unroll
      for (int t = 0; t < 4; ++t) {
        const int krow = 16 * t + l15;
        v8s kf = *(const v8s*)(kc + krow * DD + ((((4 * c + g) ^ (krow & 7))) << 3));
#pragma unroll
        for (int j = 0; j < 2; ++j)
          sacc[t][j] = __builtin_amdgcn_mfma_f32_16x16x32_bf16(kf, qf[j][c], sacc[t][j], 0, 0, 0);
      }
    }

    // online softmax in log2 domain; per-qrow stats are l15-local (2 shuffles)
    float tm[2];
#pragma unroll
    for (int j = 0; j < 2; ++j) {
      float a0 = fmaxf(fmaxf(sacc[0][j][0], sacc[0][j][1]), fmaxf(sacc[0][j][2], sacc[0][j][3]));
      float a1 = fmaxf(fmaxf(sacc[1][j][0], sacc[1][j][1]), fmaxf(sacc[1][j][2], sacc[1][j][3]));
      float a2 = fmaxf(fmaxf(sacc[2][j][0], sacc[2][j][1]), fmaxf(sacc[2][j][2], sacc[2][j][3]));
      float a3 = fmaxf(fmaxf(sacc[3][j][0], sacc[3][j][1]), fmaxf(sacc[3][j][2], sacc[3][j][3]));
      float t0 = fmaxf(fmaxf(a0, a1), fmaxf(a2, a3));
      t0 = fmaxf(t0, __shfl_xor(t0, 16));
      t0 = fmaxf(t0, __shfl_xor(t0, 32));
      tm[j] = t0;
    }
    // defer-rescale (T13): skip O-pass when max growth <= 11 (log2 units, ~e^8)
    const bool need = !__all((tm[0] - mrow[0] <= 11.0f) && (tm[1] - mrow[1] <= 11.0f));
    if (need) {
      float sc[2];
#pragma unroll
      for (int j = 0; j < 2; ++j) {
        float nm = fmaxf(mrow[j], tm[j]);
        sc[j] = exp2f(mrow[j] - nm);
        mrow[j] = nm;
        lrow[j] *= sc[j];
      }
#pragma unroll
      for (int m = 0; m < 2; ++m) {
#pragma unroll
        for (int r = 0; r < 4; ++r) {
          float s4 = __shfl(sc[m], (lane & 48) | (4 * g + r));
#pragma unroll
          for (int t = 0; t < 16; ++t) oacc[m][t][r] *= s4;
        }
      }
    }

    // P = exp2(S - m): bf16 pack, b64 writes to per-wave LDS tile [32][64]
    u16* pw = pb + w * 2048;
#pragma unroll
    for (int j = 0; j < 2; ++j) {
      const int prow = 16 * j + l15;
      float ls = 0.f;
#pragma unroll
      for (int t = 0; t < 4; ++t) {
        v4u pk;
#pragma unroll
        for (int r = 0; r < 4; ++r) {
          float e = exp2f(sacc[t][j][r] - mrow[j]);
          ls += e;
          pk[r] = f2bf(e);
        }
        *(v4u*)(pw + prow * 64 + (((2 * t + (g >> 1)) ^ (prow & 7)) << 3) + 4 * (g & 1)) = pk;
      }
      ls += __shfl_xor(ls, 16);
      ls += __shfl_xor(ls, 32);
      lrow[j] += ls;
    }

    // O += P @ V  (A = P from per-wave LDS, B = V^T tile)
#pragma unroll
    for (int kc2 = 0; kc2 < 2; ++kc2) {
      v8s pa[2];
#pragma unroll
      for (int m = 0; m < 2; ++m) {
        const int row = 16 * m + l15;
        pa[m] = *(const v8s*)(pw + row * 64 + ((((4 * kc2 + g) ^ (row & 7))) << 3));
      }
#pragma unroll
      for (int t = 0; t < 16; ++t) {
        const int d = 16 * t + l15;
        v8s bvv = *(const v8s*)(vc + d * 64 + ((((4 * kc2 + g) ^ (d & 7))) << 3));
#pragma unroll
        for (int m = 0; m < 2; ++m)
          oacc[m][t] = __builtin_amdgcn_mfma_f32_16x16x32_bf16(pa[m], bvv, oacc[m][t], 0, 0, 0);
      }
    }
  }

  // epilogue: write UNNORMALIZED partial O (f32) + per-row (m, l)
  float* ob = (slice == 0) ? o0 : o1;
  const size_t rb = (size_t)b * SS + (size_t)qt * QB;
  if (g == 0) {
#pragma unroll
    for (int j = 0; j < 2; ++j) {
      const size_t rowg = rb + 32 * w + 16 * j + l15;
      float2 v2 = make_float2(mrow[j], lrow[j]);
      *(float2*)(ml + ((size_t)slice * 16384 + rowg) * 2) = v2;
    }
  }
#pragma unroll
  for (int m = 0; m < 2; ++m)
#pragma unroll
    for (int t = 0; t < 16; ++t)
#pragma unroll
      for (int r = 0; r < 4; ++r)
        ob[(rb + 32 * w + 16 * m + 4 * g + r) * DD + 16 * t + l15] = oacc[m][t][r];
}

// ---- merge kv-split partials (or just normalize when nsplit==1) ----
__global__ __launch_bounds__(256) void combine_kernel(
    float* __restrict__ out, const float* __restrict__ o1,
    const float* __restrict__ ml, int nsplit) {
  const int tid = threadIdx.x;
  const size_t row = (size_t)blockIdx.x * 4 + (tid >> 6);
  const int d = (tid & 63) * 4;
  float2 ml0 = *(const float2*)(ml + row * 2);
  float4 a = *(const float4*)(out + row * DD + d);
  if (nsplit == 2) {
    float2 ml1 = *(const float2*)(ml + (16384 + row) * 2);
    float m = fmaxf(ml0.x, ml1.x);
    float a0 = exp2f(ml0.x - m), a1 = exp2f(ml1.x - m);
    float4 bb = *(const float4*)(o1 + row * DD + d);
    float inv = 1.0f / (a0 * ml0.y + a1 * ml1.y);
    a.x = (a0 * a.x + a1 * bb.x) * inv;
    a.y = (a0 * a.y + a1 * bb.y) * inv;
    a.z = (a0 * a.z + a1 * bb.z) * inv;
    a.w = (a0 * a.w + a1 * bb.w) * inv;
  } else {
    float inv = 1.0f / ml0.y;
    a.x *= inv; a.y *= inv; a.z *= inv; a.w *= inv;
  }
  *(float4*)(out + row * DD + d) = a;
}

extern "C" void kernel_launch(void* const* d_in, const int* in_sizes, int n_in,
                              void* d_out, int out_size, void* d_ws, size_t ws_size,
                              hipStream_t stream) {
  const float* x  = (const float*)d_in[0];
  const float* Wq = (const float*)d_in[1];
  const float* bq = (const float*)d_in[2];
  const float* Wk = (const float*)d_in[3];
  const float* bk = (const float*)d_in[4];
  const float* Wv = (const float*)d_in[5];
  const float* bv = (const float*)d_in[6];
  float* out = (float*)d_out;
  char* ws = (char*)d_ws;

  u16* wt   = (u16*)ws;                                   //   393,216 B
  u16* qg   = (u16*)(ws + 393216);                        // 8,388,608 B
  u16* kg   = (u16*)(ws + 393216 + 8388608);              // 8,388,608 B
  u16* vtg  = (u16*)(ws + 393216 + 2 * 8388608);          // 8,388,608 B
  float* ml = (float*)(ws + 25559040);                    //   262,144 B
  float* o1 = (float*)(ws + 25821184);                    // 16,777,216 B (nsplit=2 only)
  const size_t need2 = 25821184ull + 16777216ull;
  const int nsplit = (ws_size >= need2) ? 2 : 1;

  (void)hipFuncSetAttribute((const void*)attn_kernel,
                            hipFuncAttributeMaxDynamicSharedMemorySize, 147456);

  wcast_kernel<<<dim3(768), dim3(256), 0, stream>>>(Wq, Wk, Wv, wt);
  proj_kernel<<<dim3(256), dim3(256), 0, stream>>>(x, wt, bq, bk, bv, qg, kg, vtg);
  attn_kernel<<<dim3(128 * nsplit), dim3(256), 147456, stream>>>(qg, kg, vtg, out, o1, ml, nsplit);
  combine_kernel<<<dim3(4096), dim3(256), 0, stream>>>(out, o1, ml, nsplit);
}